// Round 14
// baseline (150.504 us; speedup 1.0000x reference)
//
#include <hip/hip_runtime.h>
#include <math.h>

// VQ-VAE vector quantizer for MI355X (gfx950).
// z: [32768, 64] fp32, codebook: [1024, 64] fp32.
// Outputs (flat float32, concatenated): quantized_st [32768*64], vq_loss [1],
// indices [32768] (as float), perplexity [1].
//
// R14: occupancy conclusively dead (R13 achieved 4 waves/SIMD -> slower).
// K-loop is ~38-40 us invariant to everything; added dispatches/round-trips
// since R9 all cost time. R14 = maximal fusion of the R9 monolith:
//  - codebook split+norm computed ON THE FLY in the K-loop (lane loads its
//    16 fp32 elems of the code, converts hi/lo bf16 in regs, norm via 2
//    shuffles) -> vq_prep and the bsplit round-trip eliminated
//  - vq_final fused via done-counter: last block computes perplexity+loss
//  -> ONE compute dispatch + one 4.1 KB memsetAsync.
// Numerics unchanged: 3-term split-bf16 + exact fp32 recheck (margin 1e-5).

#define D 64
#define KC 1024
#define MT 4              // 16-row m-tiles per wave
#define ROWS (MT * 16)    // 64 rows per block

typedef short short8 __attribute__((ext_vector_type(8)));
typedef short short4v __attribute__((ext_vector_type(4)));
typedef float f32x4 __attribute__((ext_vector_type(4)));

__device__ __forceinline__ unsigned short f2bf(float x) {
  unsigned int u = __float_as_uint(x);
  unsigned int r = (u + 0x7fffu + ((u >> 16) & 1u)) >> 16;
  return (unsigned short)r;
}
__device__ __forceinline__ float bf2f(unsigned short h) {
  return __uint_as_float((unsigned int)h << 16);
}

__device__ __forceinline__ void cvt8(const float4 a, const float4 b,
                                     short8& hi, short8& lo) {
  float v[8] = {a.x, a.y, a.z, a.w, b.x, b.y, b.z, b.w};
#pragma unroll
  for (int j = 0; j < 8; ++j) {
    unsigned short h = f2bf(v[j]);
    hi[j] = (short)h;
    lo[j] = (short)f2bf(v[j] - bf2f(h));
  }
}

__global__ __launch_bounds__(256, 2) void vq_all(
    const float* __restrict__ z, const float* __restrict__ cb,
    float* __restrict__ out_q, float* __restrict__ out_idx,
    unsigned int* __restrict__ hist, float* __restrict__ loss_acc,
    unsigned int* __restrict__ done, float* __restrict__ out_loss,
    float* __restrict__ out_perp, float inv_n, float inv_nd, int nblocks) {
  // A' split-bf16 z tile: [64 rows][128 inner], stride 136 (bank-skew).
  __shared__ unsigned short Ash[ROWS * 136];
  __shared__ float srzp[ROWS * 16];
  __shared__ float srz[ROWS];
  __shared__ float candd[4][ROWS][17];  // +1 pad
  __shared__ int candk[4][ROWS][17];
  __shared__ int skf[ROWS];
  __shared__ float swav[4];
  __shared__ unsigned int lhist[KC];
  __shared__ int sdone;

  const int tid = threadIdx.x;
  const int lane = tid & 63;
  const int wav = tid >> 6;
  const int quad = lane >> 4;
  const int col = lane & 15;
  const int rowbase = blockIdx.x * ROWS;

  // ---- prologue: z tile -> Ash (split bf16) + row norms + zero lhist
  const float4* z4 = (const float4*)(z + (size_t)rowbase * D);
#pragma unroll
  for (int it = 0; it < ROWS / 16; ++it) {
    int f4 = it * 256 + tid;  // row*16 + (c4/4)
    int row = f4 >> 4, c4 = (f4 & 15) * 4;
    float4 v = z4[f4];
    srzp[f4] = ((v.x * v.x + v.y * v.y) + (v.z * v.z + v.w * v.w));
    unsigned short h0 = f2bf(v.x), h1 = f2bf(v.y), h2 = f2bf(v.z),
                   h3 = f2bf(v.w);
    short4v hv = {(short)h0, (short)h1, (short)h2, (short)h3};
    short4v lv = {(short)f2bf(v.x - bf2f(h0)), (short)f2bf(v.y - bf2f(h1)),
                  (short)f2bf(v.z - bf2f(h2)), (short)f2bf(v.w - bf2f(h3))};
    *(short4v*)&Ash[row * 136 + c4] = hv;
    *(short4v*)&Ash[row * 136 + 64 + c4] = lv;
  }
#pragma unroll
  for (int j = 0; j < KC / 256; ++j) lhist[tid + 256 * j] = 0u;
  __syncthreads();
  if (tid < ROWS) {
    float s = 0.f;
#pragma unroll
    for (int i = 0; i < 16; ++i) s += srzp[tid * 16 + i];
    srz[tid] = s;
  }
  __syncthreads();

  float rzv[MT * 4];
#pragma unroll
  for (int mt = 0; mt < MT; ++mt)
#pragma unroll
    for (int reg = 0; reg < 4; ++reg)
      rzv[mt * 4 + reg] = srz[mt * 16 + quad * 4 + reg];

  // A fragments: lane holds A[m=col][k=quad*8+j].
  short8 a[MT][4];
#pragma unroll
  for (int mt = 0; mt < MT; ++mt) {
    const unsigned short* base = &Ash[(mt * 16 + col) * 136 + quad * 8];
    a[mt][0] = *(const short8*)(base + 0);    // z_hi k 0..31
    a[mt][1] = *(const short8*)(base + 32);   // z_hi k 32..63
    a[mt][2] = *(const short8*)(base + 64);   // z_lo k 0..31
    a[mt][3] = *(const short8*)(base + 96);   // z_lo k 32..63
  }

  float bestd[MT * 4];
  int bestk[MT * 4];
#pragma unroll
  for (int i = 0; i < MT * 4; ++i) {
    bestd[i] = 3.4e38f;
    bestk[i] = 0;
  }

  // ---- K-loop: 16 kt-tiles of 16 codes per wave; B loaded as fp32 from cb
  // (lane's 16 elems: k = quad*8..+7 and 32+quad*8..+7), converted to
  // hi/lo bf16 in regs; next tile's fp32 prefetched in regs.
  const int k0 = wav * 256;
  float4 nf0, nf1, nf2, nf3;
  {
    const float* cbase = cb + (size_t)(k0 + col) * D + quad * 8;
    nf0 = *(const float4*)(cbase + 0);
    nf1 = *(const float4*)(cbase + 4);
    nf2 = *(const float4*)(cbase + 32);
    nf3 = *(const float4*)(cbase + 36);
  }
  for (int kt = 0; kt < 16; ++kt) {
    const int mycode = k0 + kt * 16 + col;
    const float4 f0 = nf0, f1 = nf1, f2 = nf2, f3 = nf3;
    if (kt < 15) {
      const float* nb = cb + (size_t)(mycode + 16) * D + quad * 8;
      nf0 = *(const float4*)(nb + 0);
      nf1 = *(const float4*)(nb + 4);
      nf2 = *(const float4*)(nb + 32);
      nf3 = *(const float4*)(nb + 36);
    }
    // convert current tile: b0/b1 = e_hi (k 0..31 / 32..63), b2/b3 = e_lo
    short8 b0, b1, b2, b3;
    cvt8(f0, f1, b0, b2);
    cvt8(f2, f3, b1, b3);
    // per-code norm: lane partial over its 16 elems, then quad-group sum
    float p = 0.f;
    p = fmaf(f0.x, f0.x, p); p = fmaf(f0.y, f0.y, p);
    p = fmaf(f0.z, f0.z, p); p = fmaf(f0.w, f0.w, p);
    p = fmaf(f1.x, f1.x, p); p = fmaf(f1.y, f1.y, p);
    p = fmaf(f1.z, f1.z, p); p = fmaf(f1.w, f1.w, p);
    p = fmaf(f2.x, f2.x, p); p = fmaf(f2.y, f2.y, p);
    p = fmaf(f2.z, f2.z, p); p = fmaf(f2.w, f2.w, p);
    p = fmaf(f3.x, f3.x, p); p = fmaf(f3.y, f3.y, p);
    p = fmaf(f3.z, f3.z, p); p = fmaf(f3.w, f3.w, p);
    float q = p + __shfl_xor(p, 16, 64);
    const float en = q + __shfl_xor(q, 32, 64);

    f32x4 acc[MT];
#pragma unroll
    for (int mt = 0; mt < MT; ++mt) acc[mt] = {0.f, 0.f, 0.f, 0.f};
#pragma unroll
    for (int mt = 0; mt < MT; ++mt)
      acc[mt] = __builtin_amdgcn_mfma_f32_16x16x32_bf16(a[mt][0], b0, acc[mt], 0, 0, 0);
#pragma unroll
    for (int mt = 0; mt < MT; ++mt)
      acc[mt] = __builtin_amdgcn_mfma_f32_16x16x32_bf16(a[mt][1], b1, acc[mt], 0, 0, 0);
#pragma unroll
    for (int mt = 0; mt < MT; ++mt)
      acc[mt] = __builtin_amdgcn_mfma_f32_16x16x32_bf16(a[mt][2], b0, acc[mt], 0, 0, 0);
#pragma unroll
    for (int mt = 0; mt < MT; ++mt)
      acc[mt] = __builtin_amdgcn_mfma_f32_16x16x32_bf16(a[mt][3], b1, acc[mt], 0, 0, 0);
#pragma unroll
    for (int mt = 0; mt < MT; ++mt)
      acc[mt] = __builtin_amdgcn_mfma_f32_16x16x32_bf16(a[mt][0], b2, acc[mt], 0, 0, 0);
#pragma unroll
    for (int mt = 0; mt < MT; ++mt)
      acc[mt] = __builtin_amdgcn_mfma_f32_16x16x32_bf16(a[mt][1], b3, acc[mt], 0, 0, 0);

    // fold; C/D layout: col=lane&15, row=quad*4+reg; strict < keeps lowest k
#pragma unroll
    for (int mt = 0; mt < MT; ++mt)
#pragma unroll
      for (int reg = 0; reg < 4; ++reg) {
        float dist = fmaf(-2.0f, acc[mt][reg], rzv[mt * 4 + reg] + en);
        int i = mt * 4 + reg;
        bool better = dist < bestd[i];
        bestk[i] = better ? mycode : bestk[i];
        bestd[i] = better ? dist : bestd[i];
      }
  }

  // publish per-lane candidates: per row, 16 col-classes x 4 waves
#pragma unroll
  for (int mt = 0; mt < MT; ++mt)
#pragma unroll
    for (int reg = 0; reg < 4; ++reg) {
      int row = mt * 16 + quad * 4 + reg;
      candd[wav][row][col] = bestd[mt * 4 + reg];
      candk[wav][row][col] = bestk[mt * 4 + reg];
    }
  __syncthreads();

  // ---- per-row argmin over 64 candidates, top-2 + exact fp32 recheck
  // when margin < 1e-5 (split-dot vs fp32-dot differ <4e-7; np grid
  // quantum at dist~64 is 7.6e-6).
  if (lane < 16) {
    const int row = wav * 16 + lane;
    float bd1 = 3.4e38f, bd2 = 3.4e38f;
    int bk1 = 0x7fffffff, bk2 = 0x7fffffff;
#pragma unroll
    for (int w = 0; w < 4; ++w)
      for (int c = 0; c < 16; ++c) {
        float dv = candd[w][row][c];
        int kv = candk[w][row][c];
        bool h1 = (dv < bd1) || (dv == bd1 && kv < bk1);
        bool h2 = (dv < bd2) || (dv == bd2 && kv < bk2);
        if (h1) {
          bd2 = bd1; bk2 = bk1;
          bd1 = dv; bk1 = kv;
        } else if (h2) {
          bd2 = dv; bk2 = kv;
        }
      }
    if (bd2 - bd1 < 1e-5f) {
      // exact fp32 recompute (R3 arithmetic; norms recomputed in the same
      // 4-way-split order the old vq_prep used -> self-consistent)
      const int grow = rowbase + row;
      const float4* zp = (const float4*)(z + (size_t)grow * D);
      float s0 = 0.f, s1 = 0.f, s2 = 0.f, s3 = 0.f;
#pragma unroll
      for (int i = 0; i < 16; ++i) {
        float4 v = zp[i];
        s0 = fmaf(v.x, v.x, s0);
        s1 = fmaf(v.y, v.y, s1);
        s2 = fmaf(v.z, v.z, s2);
        s3 = fmaf(v.w, v.w, s3);
      }
      const float rzx = (s0 + s1) + (s2 + s3);
      float dx[2];
      int kk[2] = {bk1, bk2};
#pragma unroll
      for (int c = 0; c < 2; ++c) {
        const float4* e4 = (const float4*)(cb + (size_t)kk[c] * D);
        float d0 = 0.f, d1 = 0.f, d2 = 0.f, d3 = 0.f;
        float n0 = 0.f, n1 = 0.f, n2 = 0.f, n3 = 0.f;
#pragma unroll
        for (int i = 0; i < 16; ++i) {
          float4 v = e4[i];
          float4 zv = zp[i];
          d0 = fmaf(zv.x, v.x, d0);
          d1 = fmaf(zv.y, v.y, d1);
          d2 = fmaf(zv.z, v.z, d2);
          d3 = fmaf(zv.w, v.w, d3);
          n0 = fmaf(v.x, v.x, n0);
          n1 = fmaf(v.y, v.y, n1);
          n2 = fmaf(v.z, v.z, n2);
          n3 = fmaf(v.w, v.w, n3);
        }
        float dot = (d0 + d1) + (d2 + d3);
        float en = (n0 + n1) + (n2 + n3);
        dx[c] = (rzx + en) - 2.0f * dot;
      }
      if ((dx[1] < dx[0]) || (dx[1] == dx[0] && bk2 < bk1)) bk1 = bk2;
    }
    skf[row] = bk1;
    out_idx[rowbase + row] = (float)bk1;
    atomicAdd(&lhist[bk1], 1u);
  }
  __syncthreads();

  // ---- flush per-block histogram: one global atomic per distinct code
#pragma unroll
  for (int j = 0; j < KC / 256; ++j) {
    unsigned int c = lhist[tid + 256 * j];
    if (c) atomicAdd(&hist[tid + 256 * j], c);
  }

  // ---- epilogue: quantized write (exact fp32 codebook rows) + loss partial
  float lsum = 0.f;
#pragma unroll
  for (int it = 0; it < ROWS / 16; ++it) {
    int f4 = it * 256 + tid;
    int r = f4 >> 4;
    int c4 = (f4 & 15) * 4;
    int bk = skf[r];
    const float4 qv = *(const float4*)(cb + (size_t)bk * D + c4);
    const int grow = rowbase + r;
    const float4 zv = *(const float4*)(z + (size_t)grow * D + c4);
    *(float4*)(out_q + (size_t)grow * D + c4) = qv;
    float ax = qv.x - zv.x, ay = qv.y - zv.y, az = qv.z - zv.z,
          aw = qv.w - zv.w;
    lsum += ax * ax + ay * ay + az * az + aw * aw;
  }
#pragma unroll
  for (int off = 32; off > 0; off >>= 1) lsum += __shfl_down(lsum, off, 64);
  if (lane == 0) swav[wav] = lsum;
  __syncthreads();
  if (tid == 0) {
    atomicAdd(loss_acc, (swav[0] + swav[1]) + (swav[2] + swav[3]));
  }

  // ---- fused finalize: last block computes perplexity + loss scalars
  __threadfence();
  if (tid == 0) {
    unsigned int o = atomicAdd(done, 1u);
    sdone = (o == (unsigned int)(nblocks - 1)) ? 1 : 0;
  }
  __syncthreads();
  if (sdone) {
    __threadfence();
    float v = 0.f;
#pragma unroll
    for (int j = 0; j < KC / 256; ++j) {
      unsigned int c = atomicAdd(&hist[tid + 256 * j], 0u);  // coherent read
      float pr = (float)c * inv_n;
      v += pr * logf(pr + 1e-10f);
    }
#pragma unroll
    for (int off = 32; off > 0; off >>= 1) v += __shfl_down(v, off, 64);
    if (lane == 0) swav[wav] = v;
    __syncthreads();
    if (tid == 0) {
      float s = (swav[0] + swav[1]) + (swav[2] + swav[3]);
      *out_perp = expf(-s);
      float lt = atomicAdd(loss_acc, 0.f);  // coherent read
      // q_latent + 0.25*e_latent, both numerically mean((q-z)^2)
      *out_loss = 1.25f * lt * inv_nd;
    }
  }
}

extern "C" void kernel_launch(void* const* d_in, const int* in_sizes, int n_in,
                              void* d_out, int out_size, void* d_ws,
                              size_t ws_size, hipStream_t stream) {
  (void)n_in;
  (void)out_size;
  (void)ws_size;
  const float* z = (const float*)d_in[0];
  const float* cb = (const float*)d_in[1];
  const int N = in_sizes[0] / D;  // 32768

  // Output layout (flat float32, reference return order):
  float* out_q = (float*)d_out;                     // N*D
  float* out_loss = (float*)d_out + (size_t)N * D;  // 1
  float* out_idx = out_loss + 1;                    // N
  float* out_perp = out_idx + N;                    // 1

  // Workspace: hist[1024] u32 @0, loss_acc @1024, done @1025.
  unsigned int* hist = (unsigned int*)d_ws;
  float* loss_acc = (float*)d_ws + 1024;
  unsigned int* done = (unsigned int*)d_ws + 1025;

  // zero hist + loss + done (ws is poisoned 0xAA before every timed launch)
  hipMemsetAsync(d_ws, 0, 1026 * sizeof(unsigned int), stream);

  const int nblocks = N / ROWS;  // 512
  vq_all<<<dim3(nblocks), dim3(256), 0, stream>>>(
      z, cb, out_q, out_idx, hist, loss_acc, done, out_loss, out_perp,
      1.0f / (float)N, 1.0f / ((float)N * (float)D), nblocks);
}